// Round 1
// baseline (1028.685 us; speedup 1.0000x reference)
//
#include <hip/hip_runtime.h>
#include <hip/hip_bf16.h>
#include <math.h>

#define N_NODES 20000
#define N_EDGES 320000
#define NODE_DIM 64
#define EDGE_DIM 32
#define HID 128
#define HEADS 4
#define HC1 512   // HEADS*HID
#define NEG_SLOPE 0.2f
#define EB 8      // edges per wave per group
#define NG 4      // groups per wave

// order-preserving float<->uint map for atomicMax on floats
__device__ __forceinline__ unsigned omap(float f) {
  unsigned b = __float_as_uint(f);
  return (b & 0x80000000u) ? ~b : (b | 0x80000000u);
}
__device__ __forceinline__ float ounmap(unsigned u) {
  unsigned b = (u & 0x80000000u) ? (~u) : (u & 0x7fffffffu);
  // inverse: top bit set  -> original nonneg -> bits = u & 0x7fffffff
  //          top bit clear-> original negative -> bits = ~u
  b = (u & 0x80000000u) ? (u & 0x7fffffffu) : ~u;
  return __uint_as_float(b);
}
#define NEGINF_U 0x007FFFFFu   // omap(-inf)

__global__ void init_kernel(unsigned* lmax1, float* denom1, unsigned* lmax2,
                            float* denom2, int* deg) {
  int i = blockIdx.x * blockDim.x + threadIdx.x;
  if (i < N_NODES * HEADS) { lmax1[i] = NEGINF_U; denom1[i] = 0.f; }
  if (i < N_NODES) { lmax2[i] = NEGINF_U; denom2[i] = 0.f; deg[i] = 0; }
}

// xl = x @ Wl + bl ; xr = x @ Wr + br   (x:[N,64], W:[64,512])
__global__ __launch_bounds__(256) void linear1_kernel(
    const float* __restrict__ x, const float* __restrict__ Wl,
    const float* __restrict__ bl, const float* __restrict__ Wr,
    const float* __restrict__ br, float* __restrict__ xl, float* __restrict__ xr)
{
  __shared__ float xsT[NODE_DIM][16];  // x tile transposed [k][node]
  int n0 = blockIdx.x * 16;
  int t = threadIdx.x;
  {
    int flat = t * 4;            // 1024 floats total
    int i = flat >> 6, k = flat & 63;
    float4 v = *(const float4*)&x[(size_t)(n0 + i) * NODE_DIM + k];
    xsT[k + 0][i] = v.x; xsT[k + 1][i] = v.y; xsT[k + 2][i] = v.z; xsT[k + 3][i] = v.w;
  }
  __syncthreads();
  for (int m = 0; m < 2; m++) {
    const float* W  = m ? Wr : Wl;
    const float* bb = m ? br : bl;
    float* out = m ? xr : xl;
    for (int jh = 0; jh < 2; jh++) {
      int j = t + jh * 256;
      float acc[16];
      #pragma unroll
      for (int i = 0; i < 16; i++) acc[i] = 0.f;
      for (int k = 0; k < NODE_DIM; k++) {
        float w = W[k * HC1 + j];
        float xv[16];
        *(float4*)&xv[0]  = *(const float4*)&xsT[k][0];
        *(float4*)&xv[4]  = *(const float4*)&xsT[k][4];
        *(float4*)&xv[8]  = *(const float4*)&xsT[k][8];
        *(float4*)&xv[12] = *(const float4*)&xsT[k][12];
        #pragma unroll
        for (int i = 0; i < 16; i++) acc[i] = fmaf(xv[i], w, acc[i]);
      }
      float bj = bb[j];
      #pragma unroll
      for (int i = 0; i < 16; i++) out[(size_t)(n0 + i) * HC1 + j] = acc[i] + bj;
    }
  }
}

// per-edge: ee = edge_attr@We (fused, We in LDS); m=leakyrelu(xl[src]+xr[dst]+ee);
// logits[e,h] = sum_c m*att; atomicMax lmax; count degrees.
__global__ __launch_bounds__(256) void edge1_kernel(
    const float* __restrict__ ea, const int* __restrict__ srcs,
    const int* __restrict__ dsts, const float* __restrict__ We,
    const float* __restrict__ att, const float* __restrict__ xl,
    const float* __restrict__ xr, float* __restrict__ logits,
    unsigned* __restrict__ lmax, int* __restrict__ deg)
{
  __shared__ float Ws[EDGE_DIM * HC1];     // 64KB
  __shared__ float eaT[4][EDGE_DIM][EB];   // 4KB, per wave [k][e]
  int t = threadIdx.x;
  int wave = t >> 6, lane = t & 63;
  for (int i = t * 4; i < EDGE_DIM * HC1; i += 1024)
    *(float4*)&Ws[i] = *(const float4*)&We[i];
  int c0 = lane * 8;            // this lane's 8 channels (all same head)
  int h = lane >> 4;
  float atv[8];
  *(float4*)&atv[0] = *(const float4*)&att[c0];
  *(float4*)&atv[4] = *(const float4*)&att[c0 + 4];
  for (int g = 0; g < NG; g++) {
    int e0 = ((blockIdx.x * 4 + wave) * NG + g) * EB;
    __syncthreads();  // protect eaT reuse (also covers Ws staging on g==0)
    {
      float4 v = *(const float4*)&ea[(size_t)e0 * EDGE_DIM + lane * 4];
      int base = lane * 4;
      int e = base >> 5, k = base & 31;
      eaT[wave][k + 0][e] = v.x; eaT[wave][k + 1][e] = v.y;
      eaT[wave][k + 2][e] = v.z; eaT[wave][k + 3][e] = v.w;
    }
    __syncthreads();
    float acc[EB][8];
    #pragma unroll
    for (int e = 0; e < EB; e++)
      #pragma unroll
      for (int cc = 0; cc < 8; cc++) acc[e][cc] = 0.f;
    for (int k = 0; k < EDGE_DIM; k++) {
      float w[8];
      *(float4*)&w[0] = *(const float4*)&Ws[k * HC1 + c0];
      *(float4*)&w[4] = *(const float4*)&Ws[k * HC1 + c0 + 4];
      float av[EB];
      *(float4*)&av[0] = *(const float4*)&eaT[wave][k][0];
      *(float4*)&av[4] = *(const float4*)&eaT[wave][k][4];
      #pragma unroll
      for (int e = 0; e < EB; e++)
        #pragma unroll
        for (int cc = 0; cc < 8; cc++)
          acc[e][cc] = fmaf(av[e], w[cc], acc[e][cc]);
    }
    #pragma unroll
    for (int e = 0; e < EB; e++) {
      int ge = e0 + e;
      int s = srcs[ge], d = dsts[ge];
      const float* xlp = &xl[(size_t)s * HC1 + c0];
      const float* xrp = &xr[(size_t)d * HC1 + c0];
      float xlv[8], xrv[8];
      *(float4*)&xlv[0] = *(const float4*)xlp;
      *(float4*)&xlv[4] = *(const float4*)(xlp + 4);
      *(float4*)&xrv[0] = *(const float4*)xrp;
      *(float4*)&xrv[4] = *(const float4*)(xrp + 4);
      float pl = 0.f;
      #pragma unroll
      for (int cc = 0; cc < 8; cc++) {
        float z = acc[e][cc] + xlv[cc] + xrv[cc];
        float mm = z > 0.f ? z : NEG_SLOPE * z;
        pl = fmaf(mm, atv[cc], pl);
      }
      pl += __shfl_xor(pl, 1);
      pl += __shfl_xor(pl, 2);
      pl += __shfl_xor(pl, 4);
      pl += __shfl_xor(pl, 8);
      if ((lane & 15) == 0) {
        logits[(size_t)ge * HEADS + h] = pl;
        atomicMax(&lmax[(unsigned)d * HEADS + h], omap(pl));
      }
      if (lane == 0) atomicAdd(&deg[d], 1);
    }
  }
}

__global__ void ex1_kernel(const int* __restrict__ dsts, float* __restrict__ lg,
                           const unsigned* __restrict__ lmax, float* __restrict__ denom)
{
  int i = blockIdx.x * blockDim.x + threadIdx.x;
  if (i >= N_EDGES * HEADS) return;
  int e = i >> 2, h = i & 3;
  int d = dsts[e];
  float ex = expf(lg[i] - ounmap(lmax[d * HEADS + h]));
  lg[i] = ex;
  atomicAdd(&denom[d * HEADS + h], ex);
}

__global__ __launch_bounds__(1024) void scan_kernel(
    const int* __restrict__ deg, int* __restrict__ offs, int* __restrict__ cursor)
{
  __shared__ int part[1024];
  int t = threadIdx.x;
  const int C = 20;                 // 1024*20 = 20480 >= N_NODES
  int base = t * C;
  int loc[C]; int s = 0;
  #pragma unroll
  for (int i = 0; i < C; i++) { loc[i] = s; int idx = base + i; s += (idx < N_NODES) ? deg[idx] : 0; }
  part[t] = s;
  __syncthreads();
  for (int off = 1; off < 1024; off <<= 1) {
    int v = (t >= off) ? part[t - off] : 0;
    __syncthreads();
    part[t] += v;
    __syncthreads();
  }
  int pbase = (t > 0) ? part[t - 1] : 0;
  #pragma unroll
  for (int i = 0; i < C; i++) {
    int idx = base + i;
    if (idx < N_NODES) { int o = pbase + loc[i]; offs[idx] = o; cursor[idx] = o; }
  }
  if (t == 1023) offs[N_NODES] = part[1023];
}

__global__ void scatter_kernel(const int* __restrict__ dsts, int* __restrict__ cursor,
                               int* __restrict__ csr) {
  int e = blockIdx.x * blockDim.x + threadIdx.x;
  if (e >= N_EDGES) return;
  int pos = atomicAdd(&cursor[dsts[e]], 1);
  csr[pos] = e;
}

// out1[n,c] = relu( sum_{e in in(n)} alpha[e,h]*xl[src,c] + bias[c] )
__global__ __launch_bounds__(256) void agg1_kernel(
    const int* __restrict__ offs, const int* __restrict__ csr,
    const int* __restrict__ srcs, const float* __restrict__ ex,
    const float* __restrict__ denom, const float* __restrict__ xl,
    const float* __restrict__ bias, float* __restrict__ h1)
{
  int n = blockIdx.x, t = threadIdx.x;
  int c = t * 2;
  int h = c >> 7;
  float invd = 1.f / denom[n * HEADS + h];
  float a0 = 0.f, a1 = 0.f;
  int beg = offs[n], end = offs[n + 1];
  for (int i = beg; i < end; i++) {
    int e = csr[i];
    float alpha = ex[(size_t)e * HEADS + h] * invd;
    float2 v = *(const float2*)&xl[(size_t)srcs[e] * HC1 + c];
    a0 = fmaf(alpha, v.x, a0);
    a1 = fmaf(alpha, v.y, a1);
  }
  float r0 = a0 + bias[c], r1 = a1 + bias[c + 1];
  h1[(size_t)n * HC1 + c]     = r0 > 0.f ? r0 : 0.f;
  h1[(size_t)n * HC1 + c + 1] = r1 > 0.f ? r1 : 0.f;
}

// xl2 = h1 @ Wl2 + bl2 ; xr2 = h1 @ Wr2 + br2  (h1:[N,512], W:[512,128])
__global__ __launch_bounds__(256) void linear2_kernel(
    const float* __restrict__ hin, const float* __restrict__ Wl,
    const float* __restrict__ bl, const float* __restrict__ Wr,
    const float* __restrict__ br, float* __restrict__ xl, float* __restrict__ xr)
{
  __shared__ float xsT[HC1][16];   // 32KB
  int n0 = blockIdx.x * 16;
  int t = threadIdx.x;
  for (int r = 0; r < 8; r++) {
    int flat = (t + r * 256) * 4;  // 8192 floats
    int i = flat >> 9, k = flat & 511;
    float4 v = *(const float4*)&hin[(size_t)(n0 + i) * HC1 + k];
    xsT[k + 0][i] = v.x; xsT[k + 1][i] = v.y; xsT[k + 2][i] = v.z; xsT[k + 3][i] = v.w;
  }
  __syncthreads();
  int m = t >> 7, j = t & 127;
  const float* W = m ? Wr : Wl;
  float bj = (m ? br : bl)[j];
  float* out = m ? xr : xl;
  float acc[16];
  #pragma unroll
  for (int i = 0; i < 16; i++) acc[i] = 0.f;
  for (int k = 0; k < HC1; k++) {
    float w = W[k * HID + j];
    float xv[16];
    *(float4*)&xv[0]  = *(const float4*)&xsT[k][0];
    *(float4*)&xv[4]  = *(const float4*)&xsT[k][4];
    *(float4*)&xv[8]  = *(const float4*)&xsT[k][8];
    *(float4*)&xv[12] = *(const float4*)&xsT[k][12];
    #pragma unroll
    for (int i = 0; i < 16; i++) acc[i] = fmaf(xv[i], w, acc[i]);
  }
  #pragma unroll
  for (int i = 0; i < 16; i++) out[(size_t)(n0 + i) * HID + j] = acc[i] + bj;
}

__global__ __launch_bounds__(256) void edge2_kernel(
    const float* __restrict__ ea, const int* __restrict__ srcs,
    const int* __restrict__ dsts, const float* __restrict__ We,
    const float* __restrict__ att, const float* __restrict__ xl,
    const float* __restrict__ xr, float* __restrict__ logits,
    unsigned* __restrict__ lmax)
{
  __shared__ float Ws[EDGE_DIM * HID];     // 16KB
  __shared__ float eaT[4][EDGE_DIM][EB];   // 4KB
  int t = threadIdx.x;
  int wave = t >> 6, lane = t & 63;
  for (int i = t * 4; i < EDGE_DIM * HID; i += 1024)
    *(float4*)&Ws[i] = *(const float4*)&We[i];
  int c0 = lane * 2;
  float at0 = att[c0], at1 = att[c0 + 1];
  for (int g = 0; g < NG; g++) {
    int e0 = ((blockIdx.x * 4 + wave) * NG + g) * EB;
    __syncthreads();
    {
      float4 v = *(const float4*)&ea[(size_t)e0 * EDGE_DIM + lane * 4];
      int base = lane * 4;
      int e = base >> 5, k = base & 31;
      eaT[wave][k + 0][e] = v.x; eaT[wave][k + 1][e] = v.y;
      eaT[wave][k + 2][e] = v.z; eaT[wave][k + 3][e] = v.w;
    }
    __syncthreads();
    float a0[EB], a1[EB];
    #pragma unroll
    for (int e = 0; e < EB; e++) { a0[e] = 0.f; a1[e] = 0.f; }
    for (int k = 0; k < EDGE_DIM; k++) {
      float2 w = *(const float2*)&Ws[k * HID + c0];
      float av[EB];
      *(float4*)&av[0] = *(const float4*)&eaT[wave][k][0];
      *(float4*)&av[4] = *(const float4*)&eaT[wave][k][4];
      #pragma unroll
      for (int e = 0; e < EB; e++) { a0[e] = fmaf(av[e], w.x, a0[e]); a1[e] = fmaf(av[e], w.y, a1[e]); }
    }
    #pragma unroll
    for (int e = 0; e < EB; e++) {
      int ge = e0 + e;
      int s = srcs[ge], d = dsts[ge];
      float2 xlv = *(const float2*)&xl[(size_t)s * HID + c0];
      float2 xrv = *(const float2*)&xr[(size_t)d * HID + c0];
      float z0 = a0[e] + xlv.x + xrv.x;
      float z1 = a1[e] + xlv.y + xrv.y;
      float m0 = z0 > 0.f ? z0 : NEG_SLOPE * z0;
      float m1 = z1 > 0.f ? z1 : NEG_SLOPE * z1;
      float pl = m0 * at0 + m1 * at1;
      #pragma unroll
      for (int o = 1; o < 64; o <<= 1) pl += __shfl_xor(pl, o);
      if (lane == 0) {
        logits[ge] = pl;
        atomicMax(&lmax[d], omap(pl));
      }
    }
  }
}

__global__ void ex2_kernel(const int* __restrict__ dsts, float* __restrict__ lg,
                           const unsigned* __restrict__ lmax, float* __restrict__ denom) {
  int e = blockIdx.x * blockDim.x + threadIdx.x;
  if (e >= N_EDGES) return;
  int d = dsts[e];
  float ex = expf(lg[e] - ounmap(lmax[d]));
  lg[e] = ex;
  atomicAdd(&denom[d], ex);
}

__global__ __launch_bounds__(128) void agg2_kernel(
    const int* __restrict__ offs, const int* __restrict__ csr,
    const int* __restrict__ srcs, const float* __restrict__ ex,
    const float* __restrict__ denom, const float* __restrict__ xl,
    const float* __restrict__ bias, float* __restrict__ h2)
{
  int n = blockIdx.x, c = threadIdx.x;
  float invd = 1.f / denom[n];
  float acc = 0.f;
  int beg = offs[n], end = offs[n + 1];
  for (int i = beg; i < end; i++) {
    int e = csr[i];
    float alpha = ex[e] * invd;
    acc = fmaf(alpha, xl[(size_t)srcs[e] * HID + c], acc);
  }
  h2[(size_t)n * HID + c] = acc + bias[c];   // NOTE: no relu after conv2
}

__global__ __launch_bounds__(256) void head_kernel(
    const float* __restrict__ h2, const float* __restrict__ Wh1,
    const float* __restrict__ bh1, const float* __restrict__ Wh2,
    const float* __restrict__ bh2, float* __restrict__ out)
{
  __shared__ float hs[16][HID];   // 8KB
  __shared__ float ts[16][64];    // 4KB
  int n0 = blockIdx.x * 16;
  int t = threadIdx.x;
  for (int r = 0; r < 2; r++) {
    int flat = (t + r * 256) * 4; // 2048 floats
    int i = flat >> 7, k = flat & 127;
    *(float4*)&hs[i][k] = *(const float4*)&h2[(size_t)(n0 + i) * HID + k];
  }
  __syncthreads();
  int j = t & 63, g = t >> 6;
  float acc[4];
  #pragma unroll
  for (int q = 0; q < 4; q++) acc[q] = 0.f;
  for (int k = 0; k < HID; k++) {
    float w = Wh1[k * 64 + j];
    #pragma unroll
    for (int q = 0; q < 4; q++) acc[q] = fmaf(hs[g + 4 * q][k], w, acc[q]);
  }
  float bj = bh1[j];
  #pragma unroll
  for (int q = 0; q < 4; q++) {
    float v = acc[q] + bj;
    ts[g + 4 * q][j] = v > 0.f ? v : 0.f;
  }
  __syncthreads();
  if (t < 32) {
    int nl = t >> 1, k = t & 1;
    float acc2 = bh2[k];
    for (int jj = 0; jj < 64; jj++) acc2 = fmaf(ts[nl][jj], Wh2[jj * 2 + k], acc2);
    out[(size_t)(n0 + nl) * 2 + k] = acc2;
  }
}

extern "C" void kernel_launch(void* const* d_in, const int* in_sizes, int n_in,
                              void* d_out, int out_size, void* d_ws, size_t ws_size,
                              hipStream_t stream)
{
  (void)in_sizes; (void)n_in; (void)out_size; (void)ws_size;
  const float* x    = (const float*)d_in[0];
  const int* eidx   = (const int*)d_in[1];
  const float* ea   = (const float*)d_in[2];
  const float* Wl1  = (const float*)d_in[3];
  const float* bl1  = (const float*)d_in[4];
  const float* Wr1  = (const float*)d_in[5];
  const float* br1  = (const float*)d_in[6];
  const float* We1  = (const float*)d_in[7];
  const float* att1 = (const float*)d_in[8];
  const float* bias1= (const float*)d_in[9];
  const float* Wl2  = (const float*)d_in[10];
  const float* bl2  = (const float*)d_in[11];
  const float* Wr2  = (const float*)d_in[12];
  const float* br2  = (const float*)d_in[13];
  const float* We2  = (const float*)d_in[14];
  const float* att2 = (const float*)d_in[15];
  const float* bias2= (const float*)d_in[16];
  const float* Wh1  = (const float*)d_in[17];
  const float* bh1  = (const float*)d_in[18];
  const float* Wh2  = (const float*)d_in[19];
  const float* bh2  = (const float*)d_in[20];
  const int* srcs = eidx;
  const int* dsts = eidx + N_EDGES;
  float* out = (float*)d_out;

  char* p = (char*)d_ws;
  auto alloc = [&](size_t bytes) { char* q = p; p += (bytes + 511) & ~(size_t)511; return q; };
  float*    bufA   = (float*)alloc((size_t)N_NODES * HC1 * 4);   // xl1, then {xl2,xr2,h2}
  float*    bufB   = (float*)alloc((size_t)N_NODES * HC1 * 4);   // xr1, then h1
  float*    exbuf  = (float*)alloc((size_t)N_EDGES * HEADS * 4); // logits/ex L1, then L2
  unsigned* lmax1  = (unsigned*)alloc((size_t)N_NODES * HEADS * 4);
  float*    denom1 = (float*)alloc((size_t)N_NODES * HEADS * 4);
  unsigned* lmax2  = (unsigned*)alloc((size_t)N_NODES * 4);
  float*    denom2 = (float*)alloc((size_t)N_NODES * 4);
  int*      deg    = (int*)alloc((size_t)N_NODES * 4);
  int*      offs   = (int*)alloc((size_t)(N_NODES + 1) * 4);
  int*      cursor = (int*)alloc((size_t)N_NODES * 4);
  int*      csr    = (int*)alloc((size_t)N_EDGES * 4);

  float* xl1 = bufA;
  float* xr1 = bufB;
  float* h1  = bufB;                                   // overwrites xr1 (dead)
  float* xl2 = bufA;                                   // overwrites xl1 (dead)
  float* xr2 = bufA + (size_t)N_NODES * HID;
  float* h2  = bufA + (size_t)2 * N_NODES * HID;

  hipLaunchKernelGGL(init_kernel, dim3((N_NODES * HEADS + 255) / 256), dim3(256), 0, stream,
                     lmax1, denom1, lmax2, denom2, deg);
  hipLaunchKernelGGL(linear1_kernel, dim3(N_NODES / 16), dim3(256), 0, stream,
                     x, Wl1, bl1, Wr1, br1, xl1, xr1);
  hipLaunchKernelGGL(edge1_kernel, dim3(N_EDGES / (4 * NG * EB)), dim3(256), 0, stream,
                     ea, srcs, dsts, We1, att1, xl1, xr1, exbuf, lmax1, deg);
  hipLaunchKernelGGL(ex1_kernel, dim3((N_EDGES * HEADS + 255) / 256), dim3(256), 0, stream,
                     dsts, exbuf, lmax1, denom1);
  hipLaunchKernelGGL(scan_kernel, dim3(1), dim3(1024), 0, stream, deg, offs, cursor);
  hipLaunchKernelGGL(scatter_kernel, dim3((N_EDGES + 255) / 256), dim3(256), 0, stream,
                     dsts, cursor, csr);
  hipLaunchKernelGGL(agg1_kernel, dim3(N_NODES), dim3(256), 0, stream,
                     offs, csr, srcs, exbuf, denom1, xl1, bias1, h1);
  hipLaunchKernelGGL(linear2_kernel, dim3(N_NODES / 16), dim3(256), 0, stream,
                     h1, Wl2, bl2, Wr2, br2, xl2, xr2);
  hipLaunchKernelGGL(edge2_kernel, dim3(N_EDGES / (4 * NG * EB)), dim3(256), 0, stream,
                     ea, srcs, dsts, We2, att2, xl2, xr2, exbuf, lmax2);
  hipLaunchKernelGGL(ex2_kernel, dim3((N_EDGES + 255) / 256), dim3(256), 0, stream,
                     dsts, exbuf, lmax2, denom2);
  hipLaunchKernelGGL(agg2_kernel, dim3(N_NODES), dim3(128), 0, stream,
                     offs, csr, srcs, exbuf, denom2, xl2, bias2, h2);
  hipLaunchKernelGGL(head_kernel, dim3(N_NODES / 16), dim3(256), 0, stream,
                     h2, Wh1, bh1, Wh2, bh2, out);
}